// Round 1
// baseline (734.977 us; speedup 1.0000x reference)
//
#include <hip/hip_runtime.h>
#include <math.h>

#define D_MODEL 4096
#define NUM_EXPERTS 64
#define TOKENS_PER_BLOCK 64
#define KT 64                 // K-tile (floats) staged per step
#define LDS_STRIDE 65         // pad: bank = (lane + d) % 32 -> 2-way (free)
#define NSTEPS (D_MODEL / KT) // 64

__global__ __launch_bounds__(512) void router_kernel(
    const float* __restrict__ x, const float* __restrict__ W,
    const float* __restrict__ b, float* __restrict__ out, int T)
{
    // 2 x [64 tokens][65] double-buffered x tile = 8320 floats = 33.3 KB
    __shared__ float lds[2 * TOKENS_PER_BLOCK * LDS_STRIDE];

    const int tid  = threadIdx.x;
    const int wv   = __builtin_amdgcn_readfirstlane(tid >> 6); // wave id 0..7 (SGPR)
    const int lane = tid & 63;          // token-in-block for compute
    const int eg   = wv & 3;            // expert group: experts [16*eg, 16*eg+16)
    const int kh   = wv >> 1 >> 1;      // K-half of each tile (0/1)
    const int tok0 = blockIdx.x * TOKENS_PER_BLOCK;

    // staging: 1024 float4 slots (64 rows x 16), each thread handles 2
    const int p1 = tid, p2 = tid + 512;
    const int r1 = p1 >> 4, c1 = p1 & 15;
    const int r2 = p2 >> 4, c2 = p2 & 15;
    const float* xrow1 = x + (size_t)(tok0 + r1) * D_MODEL + c1 * 4;
    const float* xrow2 = x + (size_t)(tok0 + r2) * D_MODEL + c2 * 4;
    const int o1 = r1 * LDS_STRIDE + c1 * 4;
    const int o2 = r2 * LDS_STRIDE + c2 * 4;

    float acc[16];
#pragma unroll
    for (int i = 0; i < 16; i++) acc[i] = 0.f;

    // prologue: stage step 0 into buffer 0
    {
        float4 v1 = *(const float4*)(xrow1);
        float4 v2 = *(const float4*)(xrow2);
        lds[o1+0]=v1.x; lds[o1+1]=v1.y; lds[o1+2]=v1.z; lds[o1+3]=v1.w;
        lds[o2+0]=v2.x; lds[o2+1]=v2.y; lds[o2+2]=v2.z; lds[o2+3]=v2.w;
    }
    __syncthreads();

    const int dbase = kh * 32;           // this wave's half of the tile

    for (int s = 0; s < NSTEPS; s++) {
        float4 n1, n2;
        const bool more = (s + 1 < NSTEPS);
        if (more) {  // prefetch next tile into registers (latency hides under compute)
            n1 = *(const float4*)(xrow1 + (size_t)(s + 1) * KT);
            n2 = *(const float4*)(xrow2 + (size_t)(s + 1) * KT);
        }
        const float* Lc  = lds + (s & 1) * (TOKENS_PER_BLOCK * LDS_STRIDE);
        const float* xme = Lc + lane * LDS_STRIDE + dbase;
        const int kg0 = s * KT + dbase;
#pragma unroll
        for (int dc = 0; dc < 32; dc += 4) {
            const float x0 = xme[dc + 0];
            const float x1 = xme[dc + 1];
            const float x2 = xme[dc + 2];
            const float x3 = xme[dc + 3];
            const float* Wk = W + kg0 + dc;   // uniform -> scalar loads
#pragma unroll
            for (int i = 0; i < 16; i++) {
                const float* wr = Wk + (size_t)(eg * 16 + i) * D_MODEL;
                float a = acc[i];
                a = fmaf(x0, wr[0], a);
                a = fmaf(x1, wr[1], a);
                a = fmaf(x2, wr[2], a);
                a = fmaf(x3, wr[3], a);
                acc[i] = a;
            }
        }
        if (more) {
            float* Ln = lds + ((s + 1) & 1) * (TOKENS_PER_BLOCK * LDS_STRIDE);
            Ln[o1+0]=n1.x; Ln[o1+1]=n1.y; Ln[o1+2]=n1.z; Ln[o1+3]=n1.w;
            Ln[o2+0]=n2.x; Ln[o2+1]=n2.y; Ln[o2+2]=n2.z; Ln[o2+3]=n2.w;
        }
        __syncthreads();   // single barrier per iter: prev readers done before overwrite
    }

    // ---- epilogue (reuse LDS) ----
    float* accL = lds;            // [64 tokens][65] partial sums (stride-65 to dodge conflicts)
    float* cand = lds + 64 * 65;  // [4 groups][64 tokens][4] candidates

    if (kh == 1) {
#pragma unroll
        for (int i = 0; i < 16; i++)
            accL[lane * 65 + eg * 16 + i] = acc[i];
    }
    __syncthreads();

    if (kh == 0) {
        float v0 = -INFINITY, v1 = -INFINITY;
        int i0 = 0, i1 = 0;
#pragma unroll
        for (int i = 0; i < 16; i++) {
            const int e = eg * 16 + i;
            const float v = acc[i] + accL[lane * 65 + e] + b[e];
            if (v > v0)      { v1 = v0; i1 = i0; v0 = v; i0 = e; }
            else if (v > v1) { v1 = v;  i1 = e; }
        }
        float* c = cand + (eg * 64 + lane) * 4;
        c[0] = v0; c[1] = (float)i0; c[2] = v1; c[3] = (float)i1;
    }
    __syncthreads();

    if (tid < 64) {
        float v0 = -INFINITY, v1 = -INFINITY;
        float i0 = 0.f, i1 = 0.f;
#pragma unroll
        for (int g = 0; g < 4; g++) {
            const float* c = cand + (g * 64 + tid) * 4;
            const float va = c[0], ia = c[1], vb = c[2], ib = c[3];
            if (va > v0)      { v1 = v0; i1 = i0; v0 = va; i0 = ia; }
            else if (va > v1) { v1 = va; i1 = ia; }
            if (vb > v0)      { v1 = v0; i1 = i0; v0 = vb; i0 = ib; }
            else if (vb > v1) { v1 = vb; i1 = ib; }
        }
        const float e1 = expf(v1 - v0);       // v0 >= v1
        const float w0 = 1.f / (1.f + e1);
        const int tok = tok0 + tid;
        out[tok * 2 + 0] = w0;
        out[tok * 2 + 1] = e1 * w0;
        float* oi = out + (size_t)T * 2;      // indices chunk, written as float values
        oi[tok * 2 + 0] = i0;
        oi[tok * 2 + 1] = i1;
    }
}

extern "C" void kernel_launch(void* const* d_in, const int* in_sizes, int n_in,
                              void* d_out, int out_size, void* d_ws, size_t ws_size,
                              hipStream_t stream) {
    const float* x = (const float*)d_in[0];
    const float* W = (const float*)d_in[1];
    const float* b = (const float*)d_in[2];
    float* out = (float*)d_out;
    const int T = in_sizes[0] / D_MODEL;          // 16384 tokens
    const int grid = T / TOKENS_PER_BLOCK;        // 256 blocks
    hipLaunchKernelGGL(router_kernel, dim3(grid), dim3(512), 0, stream,
                       x, W, b, out, T);
}

// Round 2
// 336.801 us; speedup vs baseline: 2.1822x; 2.1822x over previous
//
#include <hip/hip_runtime.h>
#include <math.h>

#define D_MODEL 4096
#define NUM_EXPERTS 64
#define TPB 64                // tokens per block
#define KT 64                 // K-tile (floats) staged per step
#define XSTR 65               // pad: bank = (lane + d) % 32 -> 2-way (free)
#define NSTEPS (D_MODEL / KT) // 64

__global__ __launch_bounds__(1024) void router_kernel(
    const float* __restrict__ x, const float* __restrict__ W,
    const float* __restrict__ b, float* __restrict__ out, int T)
{
    __shared__ float xt[2 * TPB * XSTR];     // 33.3 KB double-buffered x tile
    __shared__ float red[12 * 64 * 17];      // 52.2 KB K-partials (3 kq x 4 eg)
    __shared__ float cand[4 * 64 * 4];       // 4 KB top-2 candidates

    const int tid  = threadIdx.x;
    const int wv   = __builtin_amdgcn_readfirstlane(tid >> 6); // wave 0..15
    const int lane = tid & 63;          // token-in-block
    const int eg   = wv & 3;            // expert group: experts [16*eg, 16*eg+16)
    const int kq   = wv >> 2;           // K-quarter of each tile (0..3)
    const int tok0 = blockIdx.x * TPB;

    // staging: 1024 float4 slots (64 rows x 16 cols), 1 per thread
    const int r = tid >> 4, c = tid & 15;
    const float* xrow = x + (size_t)(tok0 + r) * D_MODEL + c * 4;
    const int o = r * XSTR + c * 4;

    float acc[16];
#pragma unroll
    for (int i = 0; i < 16; i++) acc[i] = 0.f;

    { // prologue: stage step 0 into buffer 0
        float4 v = *(const float4*)(xrow);
        xt[o+0]=v.x; xt[o+1]=v.y; xt[o+2]=v.z; xt[o+3]=v.w;
    }
    __syncthreads();

    for (int s = 0; s < NSTEPS; s++) {
        float4 n;
        const bool more = (s + 1 < NSTEPS);
        if (more)  // prefetch next tile into registers
            n = *(const float4*)(xrow + (size_t)(s + 1) * KT);

        const float* xm = xt + (s & 1) * (TPB * XSTR) + lane * XSTR + kq * 16;
        const int kg0 = s * KT + kq * 16;
#pragma unroll
        for (int dc = 0; dc < 16; dc += 4) {
            const float x0 = xm[dc + 0];
            const float x1 = xm[dc + 1];
            const float x2 = xm[dc + 2];
            const float x3 = xm[dc + 3];
            const float* Wk = W + kg0 + dc;   // wave-uniform -> s_load
#pragma unroll
            for (int i = 0; i < 16; i++) {
                const float* wr = Wk + (size_t)(eg * 16 + i) * D_MODEL;
                float a = acc[i];
                a = fmaf(x0, wr[0], a);
                a = fmaf(x1, wr[1], a);
                a = fmaf(x2, wr[2], a);
                a = fmaf(x3, wr[3], a);
                acc[i] = a;
            }
        }
        if (more) {
            float* Ln = xt + ((s + 1) & 1) * (TPB * XSTR);
            Ln[o+0]=n.x; Ln[o+1]=n.y; Ln[o+2]=n.z; Ln[o+3]=n.w;
        }
        __syncthreads();
    }

    // ---- K reduction across the 4 kq waves ----
    if (kq > 0) {
        float* rs = red + ((kq - 1) * 4 + eg) * (64 * 17) + lane * 17;
#pragma unroll
        for (int i = 0; i < 16; i++) rs[i] = acc[i];
    }
    __syncthreads();

    if (kq == 0) {
        float v0 = -INFINITY, v1 = -INFINITY;
        int i0 = 0, i1 = 0;
#pragma unroll
        for (int i = 0; i < 16; i++) {
            const int e = eg * 16 + i;
            float v = acc[i] + b[e];
#pragma unroll
            for (int q = 0; q < 3; q++)
                v += red[(q * 4 + eg) * (64 * 17) + lane * 17 + i];
            if (v > v0)      { v1 = v0; i1 = i0; v0 = v; i0 = e; }
            else if (v > v1) { v1 = v;  i1 = e; }
        }
        float* cc = cand + (eg * 64 + lane) * 4;
        cc[0] = v0; cc[1] = (float)i0; cc[2] = v1; cc[3] = (float)i1;
    }
    __syncthreads();

    if (tid < 64) {
        float v0 = -INFINITY, v1 = -INFINITY;
        float i0 = 0.f, i1 = 0.f;
#pragma unroll
        for (int g = 0; g < 4; g++) {
            const float* cc = cand + (g * 64 + tid) * 4;
            const float va = cc[0], ia = cc[1], vb = cc[2], ib = cc[3];
            if (va > v0)      { v1 = v0; i1 = i0; v0 = va; i0 = ia; }
            else if (va > v1) { v1 = va; i1 = ia; }
            if (vb > v0)      { v1 = v0; i1 = i0; v0 = vb; i0 = ib; }
            else if (vb > v1) { v1 = vb; i1 = ib; }
        }
        const float e1 = expf(v1 - v0);       // v0 >= v1
        const float w0 = 1.f / (1.f + e1);
        const int tok = tok0 + tid;
        out[tok * 2 + 0] = w0;
        out[tok * 2 + 1] = e1 * w0;
        float* oi = out + (size_t)T * 2;      // indices chunk (float-cast)
        oi[tok * 2 + 0] = i0;
        oi[tok * 2 + 1] = i1;
    }
}

extern "C" void kernel_launch(void* const* d_in, const int* in_sizes, int n_in,
                              void* d_out, int out_size, void* d_ws, size_t ws_size,
                              hipStream_t stream) {
    const float* x = (const float*)d_in[0];
    const float* W = (const float*)d_in[1];
    const float* b = (const float*)d_in[2];
    float* out = (float*)d_out;
    const int T = in_sizes[0] / D_MODEL;          // 16384 tokens
    const int grid = T / TPB;                     // 256 blocks
    hipLaunchKernelGGL(router_kernel, dim3(grid), dim3(1024), 0, stream,
                       x, W, b, out, T);
}